// Round 2
// baseline (3484.346 us; speedup 1.0000x reference)
//
#include <hip/hip_runtime.h>

#define DEVINL __device__ __forceinline__

// ---------- constants ----------
#define INV_S3 0.57735026918962576f   // 1/sqrt(3)
#define INV_S2 0.70710678118654752f   // 1/sqrt(2)
#define C_OLD  0.89442719099991588f   // 1/sqrt(1.25)
#define A_COLD 0.44721359549995794f   // 0.5/sqrt(1.25)
#define SC_ENV 0.05590169943749474f   // (1/sqrt(20)) * (1/4)
#define SC_FS  0.17677669529663688f   // 1/sqrt(32)
#define SC_FV  0.14433756729740643f   // 1/sqrt(48)
#define SC_OUT 0.03608439182435161f   // (1/4)/sqrt(48)
#define VP 145                         // padded per-edge V stride in LDS

DEVINL float silu_f(float x) { return x / (1.f + __expf(-x)); }

DEVINL float poly_cut(float u) {
    float u2 = u * u, u4 = u2 * u2, u6 = u4 * u2;
    float f = 1.f - 28.f * u6 + 48.f * u6 * u - 21.f * u6 * u2;
    return (u < 1.f) ? f : 0.f;
}

// ---------- register-tiled GEMM helpers ----------
// At: LDS, layout [K][32] (activations transposed). Wg: global, row-major [K][NW].
// Thread computes 2 edges (er, er+1) x columns starting at c0.

template <int K, int NW>
DEVINL void gemm_2x8(const float* __restrict__ At, const float* __restrict__ Wg,
                     int er, int c0, float acc[2][8]) {
#pragma unroll 8
    for (int k = 0; k < K; ++k) {
        float2 a = *reinterpret_cast<const float2*>(At + (k << 5) + er);
        float4 w0 = *reinterpret_cast<const float4*>(Wg + k * NW + c0);
        float4 w1 = *reinterpret_cast<const float4*>(Wg + k * NW + c0 + 4);
        float wv[8] = {w0.x, w0.y, w0.z, w0.w, w1.x, w1.y, w1.z, w1.w};
#pragma unroll
        for (int j = 0; j < 8; ++j) {
            acc[0][j] = fmaf(a.x, wv[j], acc[0][j]);
            acc[1][j] = fmaf(a.y, wv[j], acc[1][j]);
        }
    }
}

template <int K, int NW>
DEVINL void gemm_2x4(const float* __restrict__ At, const float* __restrict__ Wg,
                     int er, int c0, float acc[2][4]) {
#pragma unroll 8
    for (int k = 0; k < K; ++k) {
        float2 a = *reinterpret_cast<const float2*>(At + (k << 5) + er);
        float4 w0 = *reinterpret_cast<const float4*>(Wg + k * NW + c0);
        float wv[4] = {w0.x, w0.y, w0.z, w0.w};
#pragma unroll
        for (int j = 0; j < 4; ++j) {
            acc[0][j] = fmaf(a.x, wv[j], acc[0][j]);
            acc[1][j] = fmaf(a.y, wv[j], acc[1][j]);
        }
    }
}

template <int K, int NW>
DEVINL void gemm_2x2(const float* __restrict__ At, const float* __restrict__ Wg,
                     int er, int c0, float acc[2][2]) {
#pragma unroll 8
    for (int k = 0; k < K; ++k) {
        float2 a = *reinterpret_cast<const float2*>(At + (k << 5) + er);
        float2 w0 = *reinterpret_cast<const float2*>(Wg + k * NW + c0);
        acc[0][0] = fmaf(a.x, w0.x, acc[0][0]);
        acc[0][1] = fmaf(a.x, w0.y, acc[0][1]);
        acc[1][0] = fmaf(a.y, w0.x, acc[1][0]);
        acc[1][1] = fmaf(a.y, w0.y, acc[1][1]);
    }
}

template <int K, int NW>
DEVINL void gemm_2x1(const float* __restrict__ At, const float* __restrict__ Wg,
                     int er, int c0, float acc[2]) {
#pragma unroll 8
    for (int k = 0; k < K; ++k) {
        float2 a = *reinterpret_cast<const float2*>(At + (k << 5) + er);
        float w = Wg[k * NW + c0];
        acc[0] = fmaf(a.x, w, acc[0]);
        acc[1] = fmaf(a.y, w, acc[1]);
    }
}

DEVINL void store_silu2(const float acc[2][8], float* __restrict__ Bt, int er, int c0) {
#pragma unroll
    for (int j = 0; j < 8; ++j) {
        float2 v = make_float2(silu_f(acc[0][j]), silu_f(acc[1][j]));
        *reinterpret_cast<float2*>(Bt + (c0 + j) * 32 + er) = v;
    }
}

// =====================================================================
__global__ __launch_bounds__(256) void k_zero(float* __restrict__ p, int n) {
    int i = blockIdx.x * 256 + threadIdx.x;
    if (i < n) p[i] = 0.f;
}

// =====================================================================
// K1: per-edge front: x2b -> lat (w2b MLP * cut) -> w0 (env0 MLP)
//     -> fs, fv written; es/ev scattered into raw0; lat0 (128 rows) stored.
// 32 edges / block, 256 threads.
// =====================================================================
__global__ __launch_bounds__(256) void k_edge_front(
    const float* __restrict__ g_ea, const float* __restrict__ g_na,
    const float* __restrict__ g_emb, const float* __restrict__ g_eu,
    const int* __restrict__ g_eidx,
    const float* __restrict__ w2b1, const float* __restrict__ w2b2,
    const float* __restrict__ e0w1, const float* __restrict__ e0w2,
    float* __restrict__ g_lat0, float* __restrict__ g_fs, float* __restrict__ g_fv,
    float* __restrict__ raw0, int E) {
    __shared__ __align__(16) float x2bT[16 * 32];
    __shared__ __align__(16) float Ht[128 * 32];
    __shared__ __align__(16) float Lt[128 * 32];
    __shared__ float eaS[32 * 4];
    __shared__ float cutS[32];
    __shared__ int cS[32];
    const int t = threadIdx.x;
    const int b = blockIdx.x;
    const int eb = b * 32;

    if (t < 32) {
        int e = eb + t;
        int ce = g_eidx[e];
        int ne = g_eidx[E + e];
        cS[t] = ce;
        float4 nc = *reinterpret_cast<const float4*>(g_na + ce * 4);
        float4 nn = *reinterpret_cast<const float4*>(g_na + ne * 4);
        float4 m0 = *reinterpret_cast<const float4*>(g_emb + e * 8);
        float4 m1 = *reinterpret_cast<const float4*>(g_emb + e * 8 + 4);
        x2bT[0 * 32 + t] = nc.x; x2bT[1 * 32 + t] = nc.y;
        x2bT[2 * 32 + t] = nc.z; x2bT[3 * 32 + t] = nc.w;
        x2bT[4 * 32 + t] = nn.x; x2bT[5 * 32 + t] = nn.y;
        x2bT[6 * 32 + t] = nn.z; x2bT[7 * 32 + t] = nn.w;
        x2bT[8 * 32 + t] = m0.x; x2bT[9 * 32 + t] = m0.y;
        x2bT[10 * 32 + t] = m0.z; x2bT[11 * 32 + t] = m0.w;
        x2bT[12 * 32 + t] = m1.x; x2bT[13 * 32 + t] = m1.y;
        x2bT[14 * 32 + t] = m1.z; x2bT[15 * 32 + t] = m1.w;
        float4 a4 = *reinterpret_cast<const float4*>(g_ea + e * 4);
        eaS[t * 4 + 0] = a4.x; eaS[t * 4 + 1] = a4.y;
        eaS[t * 4 + 2] = a4.z; eaS[t * 4 + 3] = a4.w;
        cutS[t] = poly_cut(g_eu[e]);
    }
    __syncthreads();

    const int eg = t & 15, cg = t >> 4;
    const int er = eg * 2;
    {
        float acc[2][8] = {};
        gemm_2x8<16, 128>(x2bT, w2b1, er, cg * 8, acc);
        store_silu2(acc, Ht, er, cg * 8);
    }
    __syncthreads();
    {
        float acc[2][8] = {};
        gemm_2x8<128, 128>(Ht, w2b2, er, cg * 8, acc);
        float cu0 = cutS[er], cu1 = cutS[er + 1];
        float* gl = g_lat0 + (size_t)b * 4096;
#pragma unroll
        for (int j = 0; j < 8; ++j) {
            float2 v = make_float2(acc[0][j] * cu0, acc[1][j] * cu1);
            *reinterpret_cast<float2*>(Lt + (cg * 8 + j) * 32 + er) = v;
            *reinterpret_cast<float2*>(gl + (cg * 8 + j) * 32 + er) = v;
        }
    }
    __syncthreads();
    {
        float acc[2][8] = {};
        gemm_2x8<128, 128>(Lt, e0w1, er, cg * 8, acc);
        store_silu2(acc, Ht, er, cg * 8);
    }
    __syncthreads();
    {
        float acc[2][4] = {};
        gemm_2x4<128, 64>(Ht, e0w2, er, cg * 4, acc);
        if (cg < 8) {
            int mA = 2 * cg, mB = 2 * cg + 1;
#pragma unroll
            for (int e2 = 0; e2 < 2; ++e2) {
                int e = er + e2;
                int ge = eb + e;
                float a0 = eaS[e * 4 + 0], a1 = eaS[e * 4 + 1];
                float a2 = eaS[e * 4 + 2], a3 = eaS[e * 4 + 3];
                g_fs[ge * 16 + mA] = acc[e2][0] * a0;
                g_fv[ge * 48 + mA * 3 + 0] = acc[e2][1] * a1;
                g_fv[ge * 48 + mA * 3 + 1] = acc[e2][1] * a2;
                g_fv[ge * 48 + mA * 3 + 2] = acc[e2][1] * a3;
                g_fs[ge * 16 + mB] = acc[e2][2] * a0;
                g_fv[ge * 48 + mB * 3 + 0] = acc[e2][3] * a1;
                g_fv[ge * 48 + mB * 3 + 1] = acc[e2][3] * a2;
                g_fv[ge * 48 + mB * 3 + 2] = acc[e2][3] * a3;
            }
        } else {
            int mA = 2 * (cg - 8), mB = 2 * (cg - 8) + 1;
#pragma unroll
            for (int e2 = 0; e2 < 2; ++e2) {
                int e = er + e2;
                int ce = cS[e];
                float a0 = eaS[e * 4 + 0], a1 = eaS[e * 4 + 1];
                float a2 = eaS[e * 4 + 2], a3 = eaS[e * 4 + 3];
                atomicAdd(&raw0[ce * 64 + mA], acc[e2][0] * a0);
                atomicAdd(&raw0[ce * 64 + 16 + mA * 3 + 0], acc[e2][1] * a1);
                atomicAdd(&raw0[ce * 64 + 16 + mA * 3 + 1], acc[e2][1] * a2);
                atomicAdd(&raw0[ce * 64 + 16 + mA * 3 + 2], acc[e2][1] * a3);
                atomicAdd(&raw0[ce * 64 + mB], acc[e2][2] * a0);
                atomicAdd(&raw0[ce * 64 + 16 + mB * 3 + 0], acc[e2][3] * a1);
                atomicAdd(&raw0[ce * 64 + 16 + mB * 3 + 1], acc[e2][3] * a2);
                atomicAdd(&raw0[ce * 64 + 16 + mB * 3 + 2], acc[e2][3] * a3);
            }
        }
    }
}

// =====================================================================
// K2: per-node env linear: lin = (raw @ envlin) * (norm*inv_sm)
// raw layout [n][64]: s at [u], v at [16 + u*3 + i]
// =====================================================================
__global__ __launch_bounds__(256) void k_node_lin(
    const float* __restrict__ raw, const float* __restrict__ wls,
    const float* __restrict__ wlv, float* __restrict__ ls, float* __restrict__ lv,
    int Nn) {
    int gid = blockIdx.x * 256 + threadIdx.x;
    if (gid >= Nn * 16) return;
    int n = gid >> 4, v = gid & 15;
    float as = 0.f, a0 = 0.f, a1 = 0.f, a2 = 0.f;
    const float* rp = raw + n * 64;
#pragma unroll
    for (int u = 0; u < 16; ++u) {
        float w1 = wls[u * 16 + v];
        float w2 = wlv[u * 16 + v];
        as = fmaf(rp[u], w1, as);
        a0 = fmaf(rp[16 + u * 3 + 0], w2, a0);
        a1 = fmaf(rp[16 + u * 3 + 1], w2, a1);
        a2 = fmaf(rp[16 + u * 3 + 2], w2, a2);
    }
    ls[n * 16 + v] = as * SC_ENV;
    lv[n * 48 + v * 3 + 0] = a0 * SC_ENV;
    lv[n * 48 + v * 3 + 1] = a1 * SC_ENV;
    lv[n * 48 + v * 3 + 2] = a2 * SC_ENV;
}

// =====================================================================
// K3 (fused): layer-0 tail + generator fold + layer-1 head.
//  gather env0 -> s1,s2 (At rows 128..159), V (LDS);
//  fold: h=silu(latent0@l2w0_w1), chunks of h@l2w0_w2 folded vs S/V -> gfs/gfv;
//  lat' = C_OLD*lat + A_COLD*cut*mlp(latent0,lat1) -> g_lat1 + At rows 0..127;
//  w_env = mlp(lat',env1) -> raw1 scatter.
// =====================================================================
__global__ __launch_bounds__(256) void k_layer0(
    const float* __restrict__ g_ea, const float* __restrict__ g_eu,
    const int* __restrict__ g_eidx,
    float* g_fs, float* g_fv,  // in: layer-0 f; out: layer-1 f (same edges)
    const float* __restrict__ ls0, const float* __restrict__ lv0,
    const float* __restrict__ lat1w1, const float* __restrict__ lat1w2,
    const float* __restrict__ e1w1, const float* __restrict__ e1w2,
    const float* __restrict__ gw1, const float* __restrict__ gw2,
    const float* __restrict__ g_lat0, float* __restrict__ g_lat1,
    float* __restrict__ raw1, int E) {
    __shared__ __align__(16) float At[160 * 32];
    __shared__ __align__(16) float Ht[128 * 32];
    __shared__ float Vs[32 * VP];
    __shared__ float fsred[32 * 16];
    __shared__ float fvred[32 * 48];
    __shared__ float eaS[32 * 4];
    __shared__ float cutS[32];
    __shared__ int cS[32];
    const int t = threadIdx.x;
    const int b = blockIdx.x;
    const int eb = b * 32;
    const float* gl0 = g_lat0 + (size_t)b * 4096;

    if (t < 32) {
        int e = eb + t;
        cS[t] = g_eidx[e];
        float4 a4 = *reinterpret_cast<const float4*>(g_ea + e * 4);
        eaS[t * 4 + 0] = a4.x; eaS[t * 4 + 1] = a4.y;
        eaS[t * 4 + 2] = a4.z; eaS[t * 4 + 3] = a4.w;
        cutS[t] = poly_cut(g_eu[e]);
    }
#pragma unroll
    for (int j = 0; j < 16; ++j) At[t + j * 256] = gl0[t + j * 256];
#pragma unroll
    for (int j = 0; j < 2; ++j) fsred[t + j * 256] = 0.f;
#pragma unroll
    for (int j = 0; j < 6; ++j) fvred[t + j * 256] = 0.f;
    __syncthreads();

    // gather + scalars + V into LDS
#pragma unroll
    for (int p = 0; p < 2; ++p) {
        int item = t + p * 256;
        int m = item >> 5, e = item & 31;
        int ge = eb + e;
        int ce = cS[e];
        float fs = g_fs[ge * 16 + m];
        float fv0 = g_fv[ge * 48 + m * 3 + 0];
        float fv1 = g_fv[ge * 48 + m * 3 + 1];
        float fv2 = g_fv[ge * 48 + m * 3 + 2];
        float es = ls0[ce * 16 + m];
        float ev0 = lv0[ce * 48 + m * 3 + 0];
        float ev1 = lv0[ce * 48 + m * 3 + 1];
        float ev2 = lv0[ce * 48 + m * 3 + 2];
        float s1 = fs * es;
        float s2 = (fv0 * ev0 + fv1 * ev1 + fv2 * ev2) * INV_S3;
        At[(128 + 2 * m) * 32 + e] = s1;
        At[(129 + 2 * m) * 32 + e] = s2;
        float* vp = Vs + e * VP;
        vp[m * 3 + 0] = fs * ev0;
        vp[m * 3 + 1] = fs * ev1;
        vp[m * 3 + 2] = fs * ev2;
        vp[48 + m * 3 + 0] = fv0 * es;
        vp[48 + m * 3 + 1] = fv1 * es;
        vp[48 + m * 3 + 2] = fv2 * es;
        vp[96 + m * 3 + 0] = (fv1 * ev2 - fv2 * ev1) * INV_S2;
        vp[96 + m * 3 + 1] = (fv2 * ev0 - fv0 * ev2) * INV_S2;
        vp[96 + m * 3 + 2] = (fv0 * ev1 - fv1 * ev0) * INV_S2;
    }
    __syncthreads();

    const int eg = t & 15, cg = t >> 4;
    const int er = eg * 2;
    const int c0 = cg * 8;

    // --- generator fold path (uses original latent0 in At) ---
    {
        float acc[2][8] = {};
        gemm_2x8<160, 128>(At, gw1, er, c0, acc);
        store_silu2(acc, Ht, er, c0);
    }
    __syncthreads();
    {
        float fsa[2][8] = {};
        float fva[2][8][3] = {};
        for (int chunk = 0; chunk < 10; ++chunk) {
            float lw[2][8] = {};
            int cc = chunk * 128 + c0;
            gemm_2x8<128, 1280>(Ht, gw2, er, cc, lw);
            int pu = cc >> 4;
            if (pu < 32) {
                int row = 128 + 2 * (pu & 15) + (pu >> 4);
#pragma unroll
                for (int e2 = 0; e2 < 2; ++e2) {
                    float s = At[row * 32 + er + e2];
#pragma unroll
                    for (int j = 0; j < 8; ++j) fsa[e2][j] = fmaf(s, lw[e2][j], fsa[e2][j]);
                }
            } else {
                int q = (pu - 32) * 3;
#pragma unroll
                for (int e2 = 0; e2 < 2; ++e2) {
                    const float* vp = Vs + (er + e2) * VP + q;
                    float v0 = vp[0], v1 = vp[1], v2 = vp[2];
#pragma unroll
                    for (int j = 0; j < 8; ++j) {
                        fva[e2][j][0] = fmaf(v0, lw[e2][j], fva[e2][j][0]);
                        fva[e2][j][1] = fmaf(v1, lw[e2][j], fva[e2][j][1]);
                        fva[e2][j][2] = fmaf(v2, lw[e2][j], fva[e2][j][2]);
                    }
                }
            }
        }
        int vb = (cg & 1) * 8;
#pragma unroll
        for (int e2 = 0; e2 < 2; ++e2) {
            int e = er + e2;
#pragma unroll
            for (int j = 0; j < 8; ++j) {
                atomicAdd(&fsred[e * 16 + vb + j], fsa[e2][j]);
                atomicAdd(&fvred[e * 48 + (vb + j) * 3 + 0], fva[e2][j][0]);
                atomicAdd(&fvred[e * 48 + (vb + j) * 3 + 1], fva[e2][j][1]);
                atomicAdd(&fvred[e * 48 + (vb + j) * 3 + 2], fva[e2][j][2]);
            }
        }
    }
    __syncthreads();
    // write layer-1 f (same edges as the gather reads; block-exclusive)
#pragma unroll
    for (int j = 0; j < 2; ++j) g_fs[eb * 16 + t + j * 256] = fsred[t + j * 256] * SC_FS;
#pragma unroll
    for (int j = 0; j < 6; ++j) g_fv[eb * 48 + t + j * 256] = fvred[t + j * 256] * SC_FV;

    // --- latent update path ---
    {
        float acc[2][8] = {};
        gemm_2x8<160, 128>(At, lat1w1, er, c0, acc);
        store_silu2(acc, Ht, er, c0);
    }
    __syncthreads();
    {
        float acc[2][8] = {};
        gemm_2x8<128, 128>(Ht, lat1w2, er, c0, acc);
        float cu0 = cutS[er], cu1 = cutS[er + 1];
        float* gl1 = g_lat1 + (size_t)b * 4096;
#pragma unroll
        for (int j = 0; j < 8; ++j) {
            float2 old = *reinterpret_cast<const float2*>(At + (c0 + j) * 32 + er);
            float n0 = C_OLD * old.x + A_COLD * cu0 * acc[0][j];
            float n1 = C_OLD * old.y + A_COLD * cu1 * acc[1][j];
            *reinterpret_cast<float2*>(gl1 + (c0 + j) * 32 + er) = make_float2(n0, n1);
            *reinterpret_cast<float2*>(At + (c0 + j) * 32 + er) = make_float2(n0, n1);
        }
    }
    __syncthreads();
    {
        float acc[2][8] = {};
        gemm_2x8<128, 128>(At, e1w1, er, c0, acc);  // K=128: reads lat' rows only
        store_silu2(acc, Ht, er, c0);
    }
    __syncthreads();
    {
        float acc[2][2] = {};
        gemm_2x2<128, 32>(Ht, e1w2, er, cg * 2, acc);
        int m = cg;
#pragma unroll
        for (int e2 = 0; e2 < 2; ++e2) {
            int e = er + e2;
            int ce = cS[e];
            float a0 = eaS[e * 4 + 0], a1 = eaS[e * 4 + 1];
            float a2 = eaS[e * 4 + 2], a3 = eaS[e * 4 + 3];
            atomicAdd(&raw1[ce * 64 + m], acc[e2][0] * a0);
            atomicAdd(&raw1[ce * 64 + 16 + m * 3 + 0], acc[e2][1] * a1);
            atomicAdd(&raw1[ce * 64 + 16 + m * 3 + 1], acc[e2][1] * a2);
            atomicAdd(&raw1[ce * 64 + 16 + m * 3 + 2], acc[e2][1] * a3);
        }
    }
}

// =====================================================================
// K5 (fused): layer-1 gather + fw MLP + generator fold (wv only) + output.
// =====================================================================
__global__ __launch_bounds__(256) void k_layer1(
    const int* __restrict__ g_eidx, const float* __restrict__ g_fs,
    const float* __restrict__ g_fv, const float* __restrict__ ls1,
    const float* __restrict__ lv1, const float* __restrict__ flw1,
    const float* __restrict__ flw2, const float* __restrict__ gw1,
    const float* __restrict__ gw2, const float* __restrict__ g_lat1,
    float* __restrict__ g_out, int E) {
    __shared__ __align__(16) float At[160 * 32];
    __shared__ __align__(16) float Ht[128 * 32];
    __shared__ float Vs[32 * VP];
    __shared__ float fvred[32 * 48];
    __shared__ float fwS[32 * 16];
    __shared__ int cS[32];
    const int t = threadIdx.x;
    const int b = blockIdx.x;
    const int eb = b * 32;
    const float* gl1 = g_lat1 + (size_t)b * 4096;

    if (t < 32) cS[t] = g_eidx[eb + t];
#pragma unroll
    for (int j = 0; j < 16; ++j) At[t + j * 256] = gl1[t + j * 256];
#pragma unroll
    for (int j = 0; j < 6; ++j) fvred[t + j * 256] = 0.f;
    __syncthreads();

#pragma unroll
    for (int p = 0; p < 2; ++p) {
        int item = t + p * 256;
        int m = item >> 5, e = item & 31;
        int ge = eb + e;
        int ce = cS[e];
        float fs = g_fs[ge * 16 + m];
        float fv0 = g_fv[ge * 48 + m * 3 + 0];
        float fv1 = g_fv[ge * 48 + m * 3 + 1];
        float fv2 = g_fv[ge * 48 + m * 3 + 2];
        float es = ls1[ce * 16 + m];
        float ev0 = lv1[ce * 48 + m * 3 + 0];
        float ev1 = lv1[ce * 48 + m * 3 + 1];
        float ev2 = lv1[ce * 48 + m * 3 + 2];
        float s1 = fs * es;
        float s2 = (fv0 * ev0 + fv1 * ev1 + fv2 * ev2) * INV_S3;
        At[(128 + 2 * m) * 32 + e] = s1;
        At[(129 + 2 * m) * 32 + e] = s2;
        float* vp = Vs + e * VP;
        vp[m * 3 + 0] = fs * ev0;
        vp[m * 3 + 1] = fs * ev1;
        vp[m * 3 + 2] = fs * ev2;
        vp[48 + m * 3 + 0] = fv0 * es;
        vp[48 + m * 3 + 1] = fv1 * es;
        vp[48 + m * 3 + 2] = fv2 * es;
        vp[96 + m * 3 + 0] = (fv1 * ev2 - fv2 * ev1) * INV_S2;
        vp[96 + m * 3 + 1] = (fv2 * ev0 - fv0 * ev2) * INV_S2;
        vp[96 + m * 3 + 2] = (fv0 * ev1 - fv1 * ev0) * INV_S2;
    }
    __syncthreads();

    const int eg = t & 15, cg = t >> 4;
    const int er = eg * 2;
    const int c0 = cg * 8;

    // fw = mlp(latent1, fl2w)
    {
        float acc[2][8] = {};
        gemm_2x8<160, 128>(At, flw1, er, c0, acc);
        store_silu2(acc, Ht, er, c0);
    }
    __syncthreads();
    {
        float acc[2] = {};
        gemm_2x1<128, 16>(Ht, flw2, er, cg, acc);
        fwS[er * 16 + cg] = acc[0];
        fwS[(er + 1) * 16 + cg] = acc[1];
    }
    __syncthreads();

    // generator fold (wv part, chunks 4..9)
    {
        float acc[2][8] = {};
        gemm_2x8<160, 128>(At, gw1, er, c0, acc);
        store_silu2(acc, Ht, er, c0);
    }
    __syncthreads();
    {
        float fva[2][8][3] = {};
        for (int chunk = 4; chunk < 10; ++chunk) {
            float lw[2][8] = {};
            int cc = chunk * 128 + c0;
            gemm_2x8<128, 1280>(Ht, gw2, er, cc, lw);
            int q = ((cc >> 4) - 32) * 3;
#pragma unroll
            for (int e2 = 0; e2 < 2; ++e2) {
                const float* vp = Vs + (er + e2) * VP + q;
                float v0 = vp[0], v1 = vp[1], v2 = vp[2];
#pragma unroll
                for (int j = 0; j < 8; ++j) {
                    fva[e2][j][0] = fmaf(v0, lw[e2][j], fva[e2][j][0]);
                    fva[e2][j][1] = fmaf(v1, lw[e2][j], fva[e2][j][1]);
                    fva[e2][j][2] = fmaf(v2, lw[e2][j], fva[e2][j][2]);
                }
            }
        }
        int vb = (cg & 1) * 8;
#pragma unroll
        for (int e2 = 0; e2 < 2; ++e2) {
            int e = er + e2;
#pragma unroll
            for (int j = 0; j < 8; ++j) {
                atomicAdd(&fvred[e * 48 + (vb + j) * 3 + 0], fva[e2][j][0]);
                atomicAdd(&fvred[e * 48 + (vb + j) * 3 + 1], fva[e2][j][1]);
                atomicAdd(&fvred[e * 48 + (vb + j) * 3 + 2], fva[e2][j][2]);
            }
        }
    }
    __syncthreads();
    if (t < 96) {
        int e = t / 3, i = t % 3;
        const float* fwp = fwS + e * 16;
        const float* fr = fvred + e * 48 + i;
        float o = 0.f;
#pragma unroll
        for (int u = 0; u < 16; ++u) o = fmaf(fwp[u], fr[u * 3], o);
        g_out[(eb + e) * 3 + i] = o * SC_OUT;
    }
}

// =====================================================================
extern "C" void kernel_launch(void* const* d_in, const int* in_sizes, int n_in,
                              void* d_out, int out_size, void* d_ws, size_t ws_size,
                              hipStream_t stream) {
    const float* g_ea = (const float*)d_in[0];
    const float* g_na = (const float*)d_in[1];
    const float* g_emb = (const float*)d_in[2];
    const float* g_eu = (const float*)d_in[3];
    const int* g_eidx = (const int*)d_in[4];
    const float* w2b1 = (const float*)d_in[5];
    const float* w2b2 = (const float*)d_in[6];
    const float* lat1w1 = (const float*)d_in[7];
    const float* lat1w2 = (const float*)d_in[8];
    const float* e0w1 = (const float*)d_in[9];
    const float* e0w2 = (const float*)d_in[10];
    const float* e1w1 = (const float*)d_in[11];
    const float* e1w2 = (const float*)d_in[12];
    const float* l2w0w1 = (const float*)d_in[13];
    const float* l2w0w2 = (const float*)d_in[14];
    const float* l2w1w1 = (const float*)d_in[15];
    const float* l2w1w2 = (const float*)d_in[16];
    const float* envws = (const float*)d_in[17];
    const float* envwv = (const float*)d_in[18];
    const float* flw1 = (const float*)d_in[19];
    const float* flw2 = (const float*)d_in[20];
    float* out = (float*)d_out;

    const int E = in_sizes[3];       // 120000
    const int Nn = in_sizes[1] / 4;  // 5000
    const int nblk = E / 32;         // 3750

    float* p = (float*)d_ws;
    float* lat0 = p; p += (size_t)nblk * 4096;
    float* lat1 = p; p += (size_t)nblk * 4096;
    float* gfs = p;  p += (size_t)E * 16;
    float* gfv = p;  p += (size_t)E * 48;
    float* raw0 = p; p += (size_t)Nn * 64;
    float* raw1 = p; p += (size_t)Nn * 64;
    float* ls0 = p;  p += (size_t)Nn * 16;
    float* lv0 = p;  p += (size_t)Nn * 48;
    float* ls1 = p;  p += (size_t)Nn * 16;
    float* lv1 = p;  p += (size_t)Nn * 48;
    // total ≈ 39.7M floats ≈ 159 MB

    const int nzero = Nn * 128;  // raw0 + raw1 contiguous
    k_zero<<<(nzero + 255) / 256, 256, 0, stream>>>(raw0, nzero);

    const int nb2 = (Nn * 16 + 255) / 256;

    k_edge_front<<<nblk, 256, 0, stream>>>(g_ea, g_na, g_emb, g_eu, g_eidx, w2b1,
                                           w2b2, e0w1, e0w2, lat0, gfs, gfv, raw0, E);
    k_node_lin<<<nb2, 256, 0, stream>>>(raw0, envws, envwv, ls0, lv0, Nn);
    k_layer0<<<nblk, 256, 0, stream>>>(g_ea, g_eu, g_eidx, gfs, gfv, ls0, lv0,
                                       lat1w1, lat1w2, e1w1, e1w2, l2w0w1, l2w0w2,
                                       lat0, lat1, raw1, E);
    k_node_lin<<<nb2, 256, 0, stream>>>(raw1, envws + 256, envwv + 256, ls1, lv1, Nn);
    k_layer1<<<nblk, 256, 0, stream>>>(g_eidx, gfs, gfv, ls1, lv1, flw1, flw2,
                                       l2w1w1, l2w1w2, lat1, out, E);
}

// Round 3
// 1132.738 us; speedup vs baseline: 3.0760x; 3.0760x over previous
//
#include <hip/hip_runtime.h>

typedef _Float16 half_t;
typedef _Float16 half8 __attribute__((ext_vector_type(8)));
typedef float f32x16 __attribute__((ext_vector_type(16)));

#define DEVINL __device__ __forceinline__

// ---------- constants ----------
#define INV_S3 0.57735026918962576f   // 1/sqrt(3)
#define INV_S2 0.70710678118654752f   // 1/sqrt(2)
#define C_OLD  0.89442719099991588f   // 1/sqrt(1.25)
#define A_COLD 0.44721359549995794f   // 0.5/sqrt(1.25)
#define SC_ENV 0.05590169943749474f   // (1/sqrt(20)) * (1/4)
#define SC_FS  0.17677669529663688f   // 1/sqrt(32)
#define SC_FV  0.14433756729740643f   // 1/sqrt(48)
#define SC_OUT 0.03608439182435161f   // (1/4)/sqrt(48)
#define VP 145                         // padded per-edge V stride in LDS (f32)
#define DS 136                         // Dstage row stride (f32): 16B-aligned rows

DEVINL float silu_f(float x) { return x / (1.f + __expf(-x)); }

DEVINL float poly_cut(float u) {
    float u2 = u * u, u4 = u2 * u2, u6 = u4 * u2;
    float f = 1.f - 28.f * u6 + 48.f * u6 * u - 21.f * u6 * u2;
    return (u < 1.f) ? f : 0.f;
}

// =====================================================================
// MFMA building blocks. M=32 edges per block.
// Afrag layout (LDS, fp16): cell(kblk,m) at halfs[(kblk*32+m)*8 + j], k = kblk*8+j
// Bfrag layout (global, fp16): cell(ntile,kblk,n) at halfs[((ntile*KB+kblk)*32+n)*8 + j]
// v_mfma_f32_32x32x16_f16 operands: A[m=lane&31][k=(lane>>5)*8+j],
// B[k=(lane>>5)*8+j][n=lane&31]; D col=lane&31, row=(r&3)+8*(r>>2)+4*(lane>>5).
// =====================================================================
template <int KB>  // KB = K/8
DEVINL f32x16 mfma_stage(const half_t* __restrict__ Afrag,
                         const half_t* __restrict__ Bfrag, int ntile, int lane) {
    const int nq = lane & 31, q = lane >> 5;
    const half_t* ap = Afrag + q * 256 + nq * 8;
    const half_t* bp = Bfrag + ((size_t)ntile * KB + q) * 256 + nq * 8;
    f32x16 acc;
#pragma unroll
    for (int i = 0; i < 16; ++i) acc[i] = 0.f;
#pragma unroll
    for (int h = 0; h < KB / 2; ++h) {
        half8 a = *reinterpret_cast<const half8*>(ap + h * 512);
        half8 b = *reinterpret_cast<const half8*>(bp + h * 512);
        acc = __builtin_amdgcn_mfma_f32_32x32x16_f16(a, b, acc, 0, 0, 0);
    }
    return acc;
}

DEVINL void dwrite(float* __restrict__ Dst, const f32x16& acc, int lane, int col0) {
    const int n = col0 + (lane & 31), q = lane >> 5;
#pragma unroll
    for (int r = 0; r < 16; ++r) {
        int m = (r & 3) + 8 * (r >> 2) + 4 * q;
        Dst[m * DS + n] = acc[r];
    }
}

// Dstage (128 cols) -> silu -> fp16 Afrag (16 kblk). 256 threads, 512 cells.
DEVINL void repack_silu(const float* __restrict__ Dst, half_t* __restrict__ Afrag,
                        int t) {
#pragma unroll
    for (int c = 0; c < 2; ++c) {
        int cell = t + c * 256;
        int kblk = cell >> 5, m = cell & 31;
        const float* s = Dst + m * DS + kblk * 8;
        half8 v;
#pragma unroll
        for (int j = 0; j < 8; ++j) v[j] = (half_t)silu_f(s[j]);
        *reinterpret_cast<half8*>(Afrag + cell * 8) = v;
    }
}

// =====================================================================
__global__ __launch_bounds__(256) void k_zero(float* __restrict__ p, int n) {
    int i = blockIdx.x * 256 + threadIdx.x;
    if (i < n) p[i] = 0.f;
}

// =====================================================================
// Weight pack: f32 [K][N] row-major -> fp16 B-fragment layout (N padded to 32).
// =====================================================================
struct PackArgs {
    const float* src[14];
    half_t* dst[14];
    int K[14];
    int N[14];
};

__global__ __launch_bounds__(256) void k_pack(PackArgs pa) {
    int mi = blockIdx.y;
    int K = pa.K[mi], N = pa.N[mi];
    int Npad = (N + 31) & ~31;
    int KB = K >> 3;
    int cells = KB * Npad;
    int cell = blockIdx.x * 256 + threadIdx.x;
    if (cell >= cells) return;
    int nn = cell & 31, r2 = cell >> 5;
    int kblk = r2 % KB, ntile = r2 / KB;
    int n = ntile * 32 + nn;
    const float* W = pa.src[mi];
    half8 v;
#pragma unroll
    for (int j = 0; j < 8; ++j) {
        int k = kblk * 8 + j;
        v[j] = (half_t)((n < N) ? W[k * N + n] : 0.f);
    }
    *reinterpret_cast<half8*>(pa.dst[mi] + (size_t)cell * 8) = v;
}

// =====================================================================
// K1: front: x2b -> lat = cut*mlp(w2b) -> w0 = mlp(env0) -> fs/fv + raw0 scatter.
// lat stored to global as fp16 Afrag image (4096 halfs per block).
// =====================================================================
__global__ __launch_bounds__(256) void k_edge_front(
    const float* __restrict__ g_ea, const float* __restrict__ g_na,
    const float* __restrict__ g_emb, const float* __restrict__ g_eu,
    const int* __restrict__ g_eidx,
    const half_t* __restrict__ b_w2b1, const half_t* __restrict__ b_w2b2,
    const half_t* __restrict__ b_e0w1, const half_t* __restrict__ b_e0w2,
    half_t* __restrict__ g_lat0, float* __restrict__ g_fs, float* __restrict__ g_fv,
    float* __restrict__ raw0, int E) {
    __shared__ __align__(16) half_t Ax[2 * 32 * 8];
    __shared__ __align__(16) half_t Al[16 * 32 * 8];
    __shared__ __align__(16) half_t Ah[16 * 32 * 8];
    __shared__ __align__(16) float Dst[32 * DS];
    __shared__ float eaS[32 * 4];
    __shared__ float cutS[32];
    __shared__ int cS[32];
    const int t = threadIdx.x, b = blockIdx.x, eb = b * 32;
    const int lane = t & 63, wave = t >> 6;

    if (t < 32) {
        int e = eb + t;
        cS[t] = g_eidx[e];
        float4 a4 = *reinterpret_cast<const float4*>(g_ea + e * 4);
        eaS[t * 4 + 0] = a4.x; eaS[t * 4 + 1] = a4.y;
        eaS[t * 4 + 2] = a4.z; eaS[t * 4 + 3] = a4.w;
        cutS[t] = poly_cut(g_eu[e]);
    }
    if (t < 64) {
        int kblk = t >> 5, m = t & 31, e = eb + m;
        half8 v;
        if (kblk == 0) {
            int ce = g_eidx[e], ne = g_eidx[E + e];
            float4 nc = *reinterpret_cast<const float4*>(g_na + ce * 4);
            float4 nn = *reinterpret_cast<const float4*>(g_na + ne * 4);
            v[0] = (half_t)nc.x; v[1] = (half_t)nc.y; v[2] = (half_t)nc.z; v[3] = (half_t)nc.w;
            v[4] = (half_t)nn.x; v[5] = (half_t)nn.y; v[6] = (half_t)nn.z; v[7] = (half_t)nn.w;
        } else {
            float4 m0 = *reinterpret_cast<const float4*>(g_emb + e * 8);
            float4 m1 = *reinterpret_cast<const float4*>(g_emb + e * 8 + 4);
            v[0] = (half_t)m0.x; v[1] = (half_t)m0.y; v[2] = (half_t)m0.z; v[3] = (half_t)m0.w;
            v[4] = (half_t)m1.x; v[5] = (half_t)m1.y; v[6] = (half_t)m1.z; v[7] = (half_t)m1.w;
        }
        *reinterpret_cast<half8*>(Ax + t * 8) = v;
    }
    __syncthreads();

    { f32x16 acc = mfma_stage<2>(Ax, b_w2b1, wave, lane); dwrite(Dst, acc, lane, wave * 32); }
    __syncthreads();
    repack_silu(Dst, Ah, t);
    __syncthreads();
    { f32x16 acc = mfma_stage<16>(Ah, b_w2b2, wave, lane); dwrite(Dst, acc, lane, wave * 32); }
    __syncthreads();
    {   // lat = cut * D -> global fp16 (Afrag image) + LDS Al
        half_t* gl = g_lat0 + (size_t)b * 4096;
#pragma unroll
        for (int c = 0; c < 2; ++c) {
            int cell = t + c * 256;
            int kblk = cell >> 5, m = cell & 31;
            const float* s = Dst + m * DS + kblk * 8;
            float cu = cutS[m];
            half8 v;
#pragma unroll
            for (int j = 0; j < 8; ++j) v[j] = (half_t)(cu * s[j]);
            *reinterpret_cast<half8*>(Al + cell * 8) = v;
            *reinterpret_cast<half8*>(gl + cell * 8) = v;
        }
    }
    __syncthreads();
    { f32x16 acc = mfma_stage<16>(Al, b_e0w1, wave, lane); dwrite(Dst, acc, lane, wave * 32); }
    __syncthreads();
    repack_silu(Dst, Ah, t);
    __syncthreads();
    if (wave < 2) { f32x16 acc = mfma_stage<16>(Ah, b_e0w2, wave, lane); dwrite(Dst, acc, lane, wave * 32); }
    __syncthreads();
    {   // tail: fs/fv + raw0 scatter (reads Dst cols 0..63)
        const int eg = t & 15, cg = t >> 4, er = eg * 2;
        float acc[2][4];
#pragma unroll
        for (int e2 = 0; e2 < 2; ++e2)
#pragma unroll
            for (int jj = 0; jj < 4; ++jj) acc[e2][jj] = Dst[(er + e2) * DS + cg * 4 + jj];
        if (cg < 8) {
            int mA = 2 * cg, mB = 2 * cg + 1;
#pragma unroll
            for (int e2 = 0; e2 < 2; ++e2) {
                int e = er + e2, ge = eb + e;
                float a0 = eaS[e * 4 + 0], a1 = eaS[e * 4 + 1];
                float a2 = eaS[e * 4 + 2], a3 = eaS[e * 4 + 3];
                g_fs[ge * 16 + mA] = acc[e2][0] * a0;
                g_fv[ge * 48 + mA * 3 + 0] = acc[e2][1] * a1;
                g_fv[ge * 48 + mA * 3 + 1] = acc[e2][1] * a2;
                g_fv[ge * 48 + mA * 3 + 2] = acc[e2][1] * a3;
                g_fs[ge * 16 + mB] = acc[e2][2] * a0;
                g_fv[ge * 48 + mB * 3 + 0] = acc[e2][3] * a1;
                g_fv[ge * 48 + mB * 3 + 1] = acc[e2][3] * a2;
                g_fv[ge * 48 + mB * 3 + 2] = acc[e2][3] * a3;
            }
        } else {
            int mA = 2 * (cg - 8), mB = 2 * (cg - 8) + 1;
#pragma unroll
            for (int e2 = 0; e2 < 2; ++e2) {
                int e = er + e2, ce = cS[e];
                float a0 = eaS[e * 4 + 0], a1 = eaS[e * 4 + 1];
                float a2 = eaS[e * 4 + 2], a3 = eaS[e * 4 + 3];
                atomicAdd(&raw0[ce * 64 + mA], acc[e2][0] * a0);
                atomicAdd(&raw0[ce * 64 + 16 + mA * 3 + 0], acc[e2][1] * a1);
                atomicAdd(&raw0[ce * 64 + 16 + mA * 3 + 1], acc[e2][1] * a2);
                atomicAdd(&raw0[ce * 64 + 16 + mA * 3 + 2], acc[e2][1] * a3);
                atomicAdd(&raw0[ce * 64 + mB], acc[e2][2] * a0);
                atomicAdd(&raw0[ce * 64 + 16 + mB * 3 + 0], acc[e2][3] * a1);
                atomicAdd(&raw0[ce * 64 + 16 + mB * 3 + 1], acc[e2][3] * a2);
                atomicAdd(&raw0[ce * 64 + 16 + mB * 3 + 2], acc[e2][3] * a3);
            }
        }
    }
}

// =====================================================================
// K2: per-node env linear (f32, unchanged).
// =====================================================================
__global__ __launch_bounds__(256) void k_node_lin(
    const float* __restrict__ raw, const float* __restrict__ wls,
    const float* __restrict__ wlv, float* __restrict__ ls, float* __restrict__ lv,
    int Nn) {
    int gid = blockIdx.x * 256 + threadIdx.x;
    if (gid >= Nn * 16) return;
    int n = gid >> 4, v = gid & 15;
    float as = 0.f, a0 = 0.f, a1 = 0.f, a2 = 0.f;
    const float* rp = raw + n * 64;
#pragma unroll
    for (int u = 0; u < 16; ++u) {
        float w1 = wls[u * 16 + v];
        float w2 = wlv[u * 16 + v];
        as = fmaf(rp[u], w1, as);
        a0 = fmaf(rp[16 + u * 3 + 0], w2, a0);
        a1 = fmaf(rp[16 + u * 3 + 1], w2, a1);
        a2 = fmaf(rp[16 + u * 3 + 2], w2, a2);
    }
    ls[n * 16 + v] = as * SC_ENV;
    lv[n * 48 + v * 3 + 0] = a0 * SC_ENV;
    lv[n * 48 + v * 3 + 1] = a1 * SC_ENV;
    lv[n * 48 + v * 3 + 2] = a2 * SC_ENV;
}

// =====================================================================
// K3 (fused, MFMA): layer-0 tail + generator fold + layer-1 head.
// =====================================================================
__global__ __launch_bounds__(256) void k_layer0(
    const float* __restrict__ g_ea, const float* __restrict__ g_eu,
    const int* __restrict__ g_eidx,
    float* g_fs, float* g_fv,
    const float* __restrict__ ls0, const float* __restrict__ lv0,
    const half_t* __restrict__ b_lat1w1, const half_t* __restrict__ b_lat1w2,
    const half_t* __restrict__ b_e1w1, const half_t* __restrict__ b_e1w2,
    const half_t* __restrict__ b_gw1, const half_t* __restrict__ b_gw2,
    const half_t* __restrict__ g_lat0, half_t* __restrict__ g_lat1,
    float* __restrict__ raw1, int E) {
    __shared__ __align__(16) half_t Al[20 * 32 * 8];  // latent_in fp16 (160 rows)
    __shared__ __align__(16) half_t Ah[16 * 32 * 8];
    __shared__ __align__(16) float Dst[32 * DS];
    __shared__ float Vs[32 * VP];
    __shared__ float fsred[512];
    __shared__ float fvred[1536];
    __shared__ float eaS[128];
    __shared__ float cutS[32];
    __shared__ int cS[32];
    const int t = threadIdx.x, b = blockIdx.x, eb = b * 32;
    const int lane = t & 63, wave = t >> 6;
    const half_t* gl0 = g_lat0 + (size_t)b * 4096;

    if (t < 32) {
        int e = eb + t;
        cS[t] = g_eidx[e];
        float4 a4 = *reinterpret_cast<const float4*>(g_ea + e * 4);
        eaS[t * 4 + 0] = a4.x; eaS[t * 4 + 1] = a4.y;
        eaS[t * 4 + 2] = a4.z; eaS[t * 4 + 3] = a4.w;
        cutS[t] = poly_cut(g_eu[e]);
    }
#pragma unroll
    for (int c = 0; c < 2; ++c) {  // latent rows 0..127 (contiguous fp16 copy)
        int cell = t + c * 256;
        *reinterpret_cast<half8*>(Al + cell * 8) =
            *reinterpret_cast<const half8*>(gl0 + cell * 8);
    }
#pragma unroll
    for (int j = 0; j < 2; ++j) fsred[t + j * 256] = 0.f;
#pragma unroll
    for (int j = 0; j < 6; ++j) fvred[t + j * 256] = 0.f;
    __syncthreads();

    // gather env0 -> scalars (Al rows 128..159, fp16) + V (f32 LDS)
#pragma unroll
    for (int p = 0; p < 2; ++p) {
        int item = t + p * 256;
        int m = item >> 5, e = item & 31;
        int ge = eb + e, ce = cS[e];
        float fs = g_fs[ge * 16 + m];
        float fv0 = g_fv[ge * 48 + m * 3 + 0];
        float fv1 = g_fv[ge * 48 + m * 3 + 1];
        float fv2 = g_fv[ge * 48 + m * 3 + 2];
        float es = ls0[ce * 16 + m];
        float ev0 = lv0[ce * 48 + m * 3 + 0];
        float ev1 = lv0[ce * 48 + m * 3 + 1];
        float ev2 = lv0[ce * 48 + m * 3 + 2];
        float s1 = fs * es;
        float s2 = (fv0 * ev0 + fv1 * ev1 + fv2 * ev2) * INV_S3;
        int row = 128 + 2 * m;
        int hidx = ((row >> 3) * 32 + e) * 8 + (row & 7);
        Al[hidx] = (half_t)s1;
        Al[hidx + 1] = (half_t)s2;
        float* vp = Vs + e * VP;
        vp[m * 3 + 0] = fs * ev0;
        vp[m * 3 + 1] = fs * ev1;
        vp[m * 3 + 2] = fs * ev2;
        vp[48 + m * 3 + 0] = fv0 * es;
        vp[48 + m * 3 + 1] = fv1 * es;
        vp[48 + m * 3 + 2] = fv2 * es;
        vp[96 + m * 3 + 0] = (fv1 * ev2 - fv2 * ev1) * INV_S2;
        vp[96 + m * 3 + 1] = (fv2 * ev0 - fv0 * ev2) * INV_S2;
        vp[96 + m * 3 + 2] = (fv0 * ev1 - fv1 * ev0) * INV_S2;
    }
    __syncthreads();

    // h = silu(latent0 @ gw1)
    { f32x16 acc = mfma_stage<20>(Al, b_gw1, wave, lane); dwrite(Dst, acc, lane, wave * 32); }
    __syncthreads();
    repack_silu(Dst, Ah, t);
    __syncthreads();

    // generator fold: 10 chunks of 128 cols
    const int eg = t & 15, cg = t >> 4, er = eg * 2, c0 = cg * 8;
    {
        float fsa[2][8] = {};
        float fva[2][8][3] = {};
        for (int chunk = 0; chunk < 10; ++chunk) {
            { f32x16 acc = mfma_stage<16>(Ah, b_gw2, chunk * 4 + wave, lane); dwrite(Dst, acc, lane, wave * 32); }
            __syncthreads();
            float lw[2][8];
#pragma unroll
            for (int e2 = 0; e2 < 2; ++e2) {
                float4 w0 = *reinterpret_cast<const float4*>(Dst + (er + e2) * DS + c0);
                float4 w1 = *reinterpret_cast<const float4*>(Dst + (er + e2) * DS + c0 + 4);
                lw[e2][0] = w0.x; lw[e2][1] = w0.y; lw[e2][2] = w0.z; lw[e2][3] = w0.w;
                lw[e2][4] = w1.x; lw[e2][5] = w1.y; lw[e2][6] = w1.z; lw[e2][7] = w1.w;
            }
            int pu = (chunk * 128 + c0) >> 4;
            if (pu < 32) {
                int row = 128 + 2 * (pu & 15) + (pu >> 4);
#pragma unroll
                for (int e2 = 0; e2 < 2; ++e2) {
                    float s = (float)Al[((row >> 3) * 32 + (er + e2)) * 8 + (row & 7)];
#pragma unroll
                    for (int j = 0; j < 8; ++j) fsa[e2][j] = fmaf(s, lw[e2][j], fsa[e2][j]);
                }
            } else {
                int q = (pu - 32) * 3;
#pragma unroll
                for (int e2 = 0; e2 < 2; ++e2) {
                    const float* vp = Vs + (er + e2) * VP + q;
                    float v0 = vp[0], v1 = vp[1], v2 = vp[2];
#pragma unroll
                    for (int j = 0; j < 8; ++j) {
                        fva[e2][j][0] = fmaf(v0, lw[e2][j], fva[e2][j][0]);
                        fva[e2][j][1] = fmaf(v1, lw[e2][j], fva[e2][j][1]);
                        fva[e2][j][2] = fmaf(v2, lw[e2][j], fva[e2][j][2]);
                    }
                }
            }
            __syncthreads();
        }
        int vb = (cg & 1) * 8;
#pragma unroll
        for (int e2 = 0; e2 < 2; ++e2) {
            int e = er + e2;
#pragma unroll
            for (int j = 0; j < 8; ++j) {
                atomicAdd(&fsred[e * 16 + vb + j], fsa[e2][j]);
                atomicAdd(&fvred[e * 48 + (vb + j) * 3 + 0], fva[e2][j][0]);
                atomicAdd(&fvred[e * 48 + (vb + j) * 3 + 1], fva[e2][j][1]);
                atomicAdd(&fvred[e * 48 + (vb + j) * 3 + 2], fva[e2][j][2]);
            }
        }
    }
    __syncthreads();
#pragma unroll
    for (int j = 0; j < 2; ++j) g_fs[eb * 16 + t + j * 256] = fsred[t + j * 256] * SC_FS;
#pragma unroll
    for (int j = 0; j < 6; ++j) g_fv[eb * 48 + t + j * 256] = fvred[t + j * 256] * SC_FV;

    // latent update: h2 = silu(latent0 @ lat1w1); new = h2 @ lat1w2
    { f32x16 acc = mfma_stage<20>(Al, b_lat1w1, wave, lane); dwrite(Dst, acc, lane, wave * 32); }
    __syncthreads();
    repack_silu(Dst, Ah, t);
    __syncthreads();
    { f32x16 acc = mfma_stage<16>(Ah, b_lat1w2, wave, lane); dwrite(Dst, acc, lane, wave * 32); }
    __syncthreads();
    {   // lat' = C_OLD*lat + A_COLD*cut*new -> g_lat1 (fp16) + Al rows 0..127
        half_t* gl1 = g_lat1 + (size_t)b * 4096;
#pragma unroll
        for (int c = 0; c < 2; ++c) {
            int cell = t + c * 256;
            int kblk = cell >> 5, m = cell & 31;
            const float* s = Dst + m * DS + kblk * 8;
            const half_t* op = gl0 + cell * 8;
            float cu = cutS[m];
            half8 v;
#pragma unroll
            for (int j = 0; j < 8; ++j) {
                float x = C_OLD * (float)op[j] + A_COLD * cu * s[j];
                v[j] = (half_t)x;
            }
            *reinterpret_cast<half8*>(Al + cell * 8) = v;
            *reinterpret_cast<half8*>(gl1 + cell * 8) = v;
        }
    }
    __syncthreads();
    // w_env = mlp(lat', env1)
    { f32x16 acc = mfma_stage<16>(Al, b_e1w1, wave, lane); dwrite(Dst, acc, lane, wave * 32); }
    __syncthreads();
    repack_silu(Dst, Ah, t);
    __syncthreads();
    if (wave == 0) { f32x16 acc = mfma_stage<16>(Ah, b_e1w2, 0, lane); dwrite(Dst, acc, lane, 0); }
    __syncthreads();
    {   // raw1 scatter (Dst cols 0..31)
        int m = cg;
#pragma unroll
        for (int e2 = 0; e2 < 2; ++e2) {
            int e = er + e2, ce = cS[e];
            float w0 = Dst[e * DS + 2 * m];
            float w1 = Dst[e * DS + 2 * m + 1];
            float a0 = eaS[e * 4 + 0], a1 = eaS[e * 4 + 1];
            float a2 = eaS[e * 4 + 2], a3 = eaS[e * 4 + 3];
            atomicAdd(&raw1[ce * 64 + m], w0 * a0);
            atomicAdd(&raw1[ce * 64 + 16 + m * 3 + 0], w1 * a1);
            atomicAdd(&raw1[ce * 64 + 16 + m * 3 + 1], w1 * a2);
            atomicAdd(&raw1[ce * 64 + 16 + m * 3 + 2], w1 * a3);
        }
    }
}

// =====================================================================
// K5 (fused, MFMA): layer-1 gather + fw MLP + generator fold (wv) + output.
// =====================================================================
__global__ __launch_bounds__(256) void k_layer1(
    const int* __restrict__ g_eidx, const float* __restrict__ g_fs,
    const float* __restrict__ g_fv, const float* __restrict__ ls1,
    const float* __restrict__ lv1,
    const half_t* __restrict__ b_flw1, const half_t* __restrict__ b_flw2,
    const half_t* __restrict__ b_gw1, const half_t* __restrict__ b_gw2,
    const half_t* __restrict__ g_lat1, float* __restrict__ g_out, int E) {
    __shared__ __align__(16) half_t Al[20 * 32 * 8];
    __shared__ __align__(16) half_t Ah[16 * 32 * 8];
    __shared__ __align__(16) float Dst[32 * DS];
    __shared__ float Vs[32 * VP];
    __shared__ float fvred[1536];
    __shared__ float fwS[512];
    __shared__ int cS[32];
    const int t = threadIdx.x, b = blockIdx.x, eb = b * 32;
    const int lane = t & 63, wave = t >> 6;
    const half_t* gl1 = g_lat1 + (size_t)b * 4096;

    if (t < 32) cS[t] = g_eidx[eb + t];
#pragma unroll
    for (int c = 0; c < 2; ++c) {
        int cell = t + c * 256;
        *reinterpret_cast<half8*>(Al + cell * 8) =
            *reinterpret_cast<const half8*>(gl1 + cell * 8);
    }
#pragma unroll
    for (int j = 0; j < 6; ++j) fvred[t + j * 256] = 0.f;
    __syncthreads();

#pragma unroll
    for (int p = 0; p < 2; ++p) {
        int item = t + p * 256;
        int m = item >> 5, e = item & 31;
        int ge = eb + e, ce = cS[e];
        float fs = g_fs[ge * 16 + m];
        float fv0 = g_fv[ge * 48 + m * 3 + 0];
        float fv1 = g_fv[ge * 48 + m * 3 + 1];
        float fv2 = g_fv[ge * 48 + m * 3 + 2];
        float es = ls1[ce * 16 + m];
        float ev0 = lv1[ce * 48 + m * 3 + 0];
        float ev1 = lv1[ce * 48 + m * 3 + 1];
        float ev2 = lv1[ce * 48 + m * 3 + 2];
        float s1 = fs * es;
        float s2 = (fv0 * ev0 + fv1 * ev1 + fv2 * ev2) * INV_S3;
        int row = 128 + 2 * m;
        int hidx = ((row >> 3) * 32 + e) * 8 + (row & 7);
        Al[hidx] = (half_t)s1;
        Al[hidx + 1] = (half_t)s2;
        float* vp = Vs + e * VP;
        vp[m * 3 + 0] = fs * ev0;
        vp[m * 3 + 1] = fs * ev1;
        vp[m * 3 + 2] = fs * ev2;
        vp[48 + m * 3 + 0] = fv0 * es;
        vp[48 + m * 3 + 1] = fv1 * es;
        vp[48 + m * 3 + 2] = fv2 * es;
        vp[96 + m * 3 + 0] = (fv1 * ev2 - fv2 * ev1) * INV_S2;
        vp[96 + m * 3 + 1] = (fv2 * ev0 - fv0 * ev2) * INV_S2;
        vp[96 + m * 3 + 2] = (fv0 * ev1 - fv1 * ev0) * INV_S2;
    }
    __syncthreads();

    // fw = mlp(latent1, fl2w)
    { f32x16 acc = mfma_stage<20>(Al, b_flw1, wave, lane); dwrite(Dst, acc, lane, wave * 32); }
    __syncthreads();
    repack_silu(Dst, Ah, t);
    __syncthreads();
    if (wave == 0) { f32x16 acc = mfma_stage<16>(Ah, b_flw2, 0, lane); dwrite(Dst, acc, lane, 0); }
    __syncthreads();
#pragma unroll
    for (int c = 0; c < 2; ++c) {
        int idx = t + c * 256;
        fwS[idx] = Dst[(idx >> 4) * DS + (idx & 15)];
    }
    __syncthreads();

    // h = silu(latent1 @ gw1); fold chunks 4..9 vs V
    { f32x16 acc = mfma_stage<20>(Al, b_gw1, wave, lane); dwrite(Dst, acc, lane, wave * 32); }
    __syncthreads();
    repack_silu(Dst, Ah, t);
    __syncthreads();

    const int eg = t & 15, cg = t >> 4, er = eg * 2, c0 = cg * 8;
    {
        float fva[2][8][3] = {};
        for (int chunk = 4; chunk < 10; ++chunk) {
            { f32x16 acc = mfma_stage<16>(Ah, b_gw2, chunk * 4 + wave, lane); dwrite(Dst, acc, lane, wave * 32); }
            __syncthreads();
            float lw[2][8];
#pragma unroll
            for (int e2 = 0; e2 < 2; ++e2) {
                float4 w0 = *reinterpret_cast<const float4*>(Dst + (er + e2) * DS + c0);
                float4 w1 = *reinterpret_cast<const float4*>(Dst + (er + e2) * DS + c0 + 4);
                lw[e2][0] = w0.x; lw[e2][1] = w0.y; lw[e2][2] = w0.z; lw[e2][3] = w0.w;
                lw[e2][4] = w1.x; lw[e2][5] = w1.y; lw[e2][6] = w1.z; lw[e2][7] = w1.w;
            }
            int q = (((chunk * 128 + c0) >> 4) - 32) * 3;
#pragma unroll
            for (int e2 = 0; e2 < 2; ++e2) {
                const float* vp = Vs + (er + e2) * VP + q;
                float v0 = vp[0], v1 = vp[1], v2 = vp[2];
#pragma unroll
                for (int j = 0; j < 8; ++j) {
                    fva[e2][j][0] = fmaf(v0, lw[e2][j], fva[e2][j][0]);
                    fva[e2][j][1] = fmaf(v1, lw[e2][j], fva[e2][j][1]);
                    fva[e2][j][2] = fmaf(v2, lw[e2][j], fva[e2][j][2]);
                }
            }
            __syncthreads();
        }
        int vb = (cg & 1) * 8;
#pragma unroll
        for (int e2 = 0; e2 < 2; ++e2) {
            int e = er + e2;
#pragma unroll
            for (int j = 0; j < 8; ++j) {
                atomicAdd(&fvred[e * 48 + (vb + j) * 3 + 0], fva[e2][j][0]);
                atomicAdd(&fvred[e * 48 + (vb + j) * 3 + 1], fva[e2][j][1]);
                atomicAdd(&fvred[e * 48 + (vb + j) * 3 + 2], fva[e2][j][2]);
            }
        }
    }
    __syncthreads();
    if (t < 96) {
        int e = t / 3, i = t % 3;
        const float* fwp = fwS + e * 16;
        const float* fr = fvred + e * 48 + i;
        float o = 0.f;
#pragma unroll
        for (int u = 0; u < 16; ++u) o = fmaf(fwp[u], fr[u * 3], o);
        g_out[(eb + e) * 3 + i] = o * SC_OUT;
    }
}

// =====================================================================
extern "C" void kernel_launch(void* const* d_in, const int* in_sizes, int n_in,
                              void* d_out, int out_size, void* d_ws, size_t ws_size,
                              hipStream_t stream) {
    const float* g_ea = (const float*)d_in[0];
    const float* g_na = (const float*)d_in[1];
    const float* g_emb = (const float*)d_in[2];
    const float* g_eu = (const float*)d_in[3];
    const int* g_eidx = (const int*)d_in[4];
    const float* w2b1 = (const float*)d_in[5];
    const float* w2b2 = (const float*)d_in[6];
    const float* lat1w1 = (const float*)d_in[7];
    const float* lat1w2 = (const float*)d_in[8];
    const float* e0w1 = (const float*)d_in[9];
    const float* e0w2 = (const float*)d_in[10];
    const float* e1w1 = (const float*)d_in[11];
    const float* e1w2 = (const float*)d_in[12];
    const float* l2w0w1 = (const float*)d_in[13];
    const float* l2w0w2 = (const float*)d_in[14];
    const float* l2w1w1 = (const float*)d_in[15];
    const float* l2w1w2 = (const float*)d_in[16];
    const float* envws = (const float*)d_in[17];
    const float* envwv = (const float*)d_in[18];
    const float* flw1 = (const float*)d_in[19];
    const float* flw2 = (const float*)d_in[20];
    float* out = (float*)d_out;

    const int E = in_sizes[3];       // 120000
    const int Nn = in_sizes[1] / 4;  // 5000
    const int nblk = E / 32;         // 3750

    float* p = (float*)d_ws;
    float* gfs = p;  p += (size_t)E * 16;
    float* gfv = p;  p += (size_t)E * 48;
    float* raw0 = p; p += (size_t)Nn * 64;
    float* raw1 = p; p += (size_t)Nn * 64;
    float* ls0 = p;  p += (size_t)Nn * 16;
    float* lv0 = p;  p += (size_t)Nn * 48;
    float* ls1 = p;  p += (size_t)Nn * 16;
    float* lv1 = p;  p += (size_t)Nn * 48;
    half_t* hp = (half_t*)p;
    half_t* lat0h = hp; hp += (size_t)nblk * 4096;
    half_t* lat1h = hp; hp += (size_t)nblk * 4096;

    // Bfrag fp16 weight buffers (pack layout), sizes = K * ceil32(N)
    const int KN[14][2] = {{16, 128}, {128, 128}, {128, 128}, {128, 64},
                           {160, 128}, {128, 128}, {128, 128}, {128, 32},
                           {160, 128}, {128, 1280}, {160, 128}, {128, 1280},
                           {160, 128}, {128, 16}};
    const float* srcs[14] = {w2b1, w2b2, e0w1, e0w2, lat1w1, lat1w2, e1w1, e1w2,
                             l2w0w1, l2w0w2, l2w1w1, l2w1w2, flw1, flw2};
    PackArgs pa;
    half_t* bptr[14];
    for (int i = 0; i < 14; ++i) {
        int K = KN[i][0], N = KN[i][1];
        int Npad = (N + 31) & ~31;
        bptr[i] = hp;
        hp += (size_t)K * Npad;
        pa.src[i] = srcs[i];
        pa.dst[i] = bptr[i];
        pa.K[i] = K;
        pa.N[i] = N;
    }

    k_pack<<<dim3(80, 14), 256, 0, stream>>>(pa);

    const int nzero = Nn * 128;  // raw0 + raw1 contiguous
    k_zero<<<(nzero + 255) / 256, 256, 0, stream>>>(raw0, nzero);

    const int nb2 = (Nn * 16 + 255) / 256;

    k_edge_front<<<nblk, 256, 0, stream>>>(g_ea, g_na, g_emb, g_eu, g_eidx,
                                           bptr[0], bptr[1], bptr[2], bptr[3],
                                           lat0h, gfs, gfv, raw0, E);
    k_node_lin<<<nb2, 256, 0, stream>>>(raw0, envws, envwv, ls0, lv0, Nn);
    k_layer0<<<nblk, 256, 0, stream>>>(g_ea, g_eu, g_eidx, gfs, gfv, ls0, lv0,
                                       bptr[4], bptr[5], bptr[6], bptr[7],
                                       bptr[8], bptr[9], lat0h, lat1h, raw1, E);
    k_node_lin<<<nb2, 256, 0, stream>>>(raw1, envws + 256, envwv + 256, ls1, lv1, Nn);
    k_layer1<<<nblk, 256, 0, stream>>>(g_eidx, gfs, gfv, ls1, lv1,
                                       bptr[12], bptr[13], bptr[10], bptr[11],
                                       lat1h, out, E);
}